// Round 14
// baseline (180.251 us; speedup 1.0000x reference)
//
#include <hip/hip_runtime.h>
#include <hip/hip_bf16.h>
#include <stdint.h>

#define NB 2
#define SEQ 1024
#define DMODEL 768
#define NH 12
#define DH 64
#define SCALE 0.125f
#define LOG2E 1.44269504088896f
#define NCH 4          // column chunks in fused attention

// attJ (per buffer): [16 rows][32 cols][20 j]  j-stride 20 shorts, row-stride 648
#define AJ_RS 648
// combT (per buffer): [12 heads][16 rows][40 cols-pad], head-stride 648 shorts
#define CT_HS 648

typedef __hip_bfloat16 bf16;
typedef __attribute__((ext_vector_type(8))) short short8;   // 8 x bf16 = 4 VGPRs
typedef __attribute__((ext_vector_type(4))) short short4v;  // 4 x bf16 (8B)
typedef __attribute__((ext_vector_type(2))) short s2v;      // 2 x bf16 (4B aligned)
typedef __attribute__((ext_vector_type(4))) float f32x4;    // MFMA C/D
typedef unsigned long long u64;

__device__ __forceinline__ bf16 f2b(float x){ return __float2bfloat16(x); }
__device__ __forceinline__ short f2bs(float x){
  bf16 h = __float2bfloat16(x); return *reinterpret_cast<short*>(&h);
}
__device__ __forceinline__ float s2f(short u){
  return __uint_as_float(((unsigned)(unsigned short)u) << 16);
}

// async global->LDS 16B: LDS dest wave-uniform base; HW adds lane*16.
__device__ __forceinline__ void gl_lds16(const bf16* g, bf16* l){
  __builtin_amdgcn_global_load_lds(
      (const __attribute__((address_space(1))) void*)g,
      (__attribute__((address_space(3))) void*)l, 16, 0, 0);
}

// ---------------- merged prelude: LN rows (wave-reduce) | weight cvt (float4) | M + lsum zero ----------------
__global__ __launch_bounds__(256) void prep_all(const float* __restrict__ x,
                                                const float* __restrict__ g,
                                                const float* __restrict__ bta,
                                                const float* __restrict__ w1, int n1,
                                                const float* __restrict__ w2, int n2,
                                                const float* __restrict__ theta,
                                                const float* __restrict__ gnn,
                                                bf16* __restrict__ xn,
                                                bf16* __restrict__ wb,
                                                bf16* __restrict__ Mb,
                                                float* __restrict__ l){
  int bx = blockIdx.x, t = threadIdx.x;
  if (bx < 2048){
    const float* xr = x + (size_t)bx*DMODEL;
    float v0[3]; float s = 0.f, s2 = 0.f;
    #pragma unroll
    for (int i=0;i<3;i++){ float val = xr[t+256*i]; v0[i]=val; s+=val; s2+=val*val; }
    // wave-level reduce (6 shfl steps) + 4-partial LDS combine: 1 barrier vs old 8
    #pragma unroll
    for (int m=1;m<64;m<<=1){ s += __shfl_xor(s,m); s2 += __shfl_xor(s2,m); }
    __shared__ float pw[4], pw2[4];
    int wv = t>>6;
    if ((t&63)==0){ pw[wv]=s; pw2[wv]=s2; }
    __syncthreads();
    float fs  = pw[0]+pw[1]+pw[2]+pw[3];
    float fs2 = pw2[0]+pw2[1]+pw2[2]+pw2[3];
    float mean = fs*(1.f/DMODEL);
    float var  = fs2*(1.f/DMODEL) - mean*mean;
    float rstd = rsqrtf(var + 1e-5f);
    #pragma unroll
    for (int i=0;i<3;i++){
      int c = t+256*i;
      xn[(size_t)bx*DMODEL + c] = f2b((v0[i]-mean)*rstd*g[c] + bta[c]);
    }
  } else if (bx < 2048+2304){
    // weight cvt, float4-vectorized: (n1+n2)/4 = 589824 elems4 = 2304 blocks x 256
    int i = ((bx-2048)*256 + t)*4;         // n1 divisible by 4 -> no straddle
    const float* src = (i < n1) ? (w1 + i) : (w2 + (i - n1));
    float4 v = *(const float4*)src;
    short4v o = { f2bs(v.x), f2bs(v.y), f2bs(v.z), f2bs(v.w) };
    *(short4v*)&wb[i] = o;
  } else {
    int sub = bx - (2048+2304);
    if (sub == 0){
      // M = (-0.5*theta) @ gnn_w, zero-padded to [16][16] (K=16 mix), split hi+lo bf16
      if (t < 256){
        int i = t >> 4, j = t & 15;
        float sacc = 0.f;
        if (i < 12 && j < 12)
          for (int jj=0;jj<12;jj++) sacc += (-0.5f)*theta[i*12+jj] * gnn[jj*12+j];
        bf16 hi = f2b(sacc);
        float lo = sacc - __bfloat162float(hi);
        Mb[t]       = hi;
        Mb[256 + t] = f2b(lo);
      }
    } else {
      l[(sub-1)*256 + t] = 0.f;    // 96*256 = 24576 = 2*12*1024
    }
  }
}

// ---------------- QKV GEMM (MFMA, 128x64 tiles, LDS-dbuf 1-bar/K-step) ----------------
// grid (36,16)=576 blocks = 2.25/CU (r11-verified). r13: double-buffered LDS,
// ONE barrier per K-step (24 vs 48 barrier regions): loads for step i+1 issue right
// after the barrier and land during step-i compute; the next barrier's vmcnt drain
// finds them complete. Write buf^1 while reading buf -> race-free by the single bar.
// Q pre-scaled by SCALE*LOG2E so attn_sums can use exp2f.
__global__ __launch_bounds__(256) void gemm_qkv(const bf16* __restrict__ A,
                                                const bf16* __restrict__ W,
                                                bf16* __restrict__ q,
                                                bf16* __restrict__ k,
                                                bf16* __restrict__ vt){
  __shared__ bf16 As[2][128*32];
  __shared__ bf16 Bs[2][64*32];
  int n0 = blockIdx.x*64, m0 = blockIdx.y*128;
  int t = threadIdx.x, w = t>>6, lane = t&63;
  int ln16 = lane&15, q8 = (lane>>4)*8;
  int wm = w>>1, wn = w&1;
  f32x4 acc[4][2] = {};
  int rB = t>>2, koB = (t&3)*8;
  // prologue: stage K-step 0 into buffer 0
  #pragma unroll
  for (int i=0;i<2;i++){
    int cc = t + i*256;
    int r = cc>>2, ko = (cc&3)*8;
    gl_lds16(&A[(size_t)(m0+r)*768 + ko], &As[0][(size_t)(w*64 + i*256)*8]);
  }
  gl_lds16(&W[(size_t)(n0+rB)*768 + koB], &Bs[0][(size_t)(w*64)*8]);
  for (int it=0; it<24; it++){
    int buf = it&1;
    __syncthreads();          // buf ready (vmcnt drained at bar); buf^1 free
    if (it < 23){
      int k0n = (it+1)*32;
      #pragma unroll
      for (int i=0;i<2;i++){
        int cc = t + i*256;
        int r = cc>>2, ko = (cc&3)*8;
        gl_lds16(&A[(size_t)(m0+r)*768 + k0n+ko], &As[buf^1][(size_t)(w*64 + i*256)*8]);
      }
      gl_lds16(&W[(size_t)(n0+rB)*768 + k0n+koB], &Bs[buf^1][(size_t)(w*64)*8]);
    }
    short8 af[4], bfr[2];
    #pragma unroll
    for (int mi=0;mi<4;mi++) af[mi]  = *(const short8*)&As[buf][(wm*64+mi*16+ln16)*32 + q8];
    #pragma unroll
    for (int ni=0;ni<2;ni++) bfr[ni] = *(const short8*)&Bs[buf][(wn*32+ni*16+ln16)*32 + q8];
    #pragma unroll
    for (int mi=0;mi<4;mi++)
      #pragma unroll
      for (int ni=0;ni<2;ni++)
        acc[mi][ni] = __builtin_amdgcn_mfma_f32_16x16x32_bf16(af[mi], bfr[ni], acc[mi][ni], 0, 0, 0);
  }
  int quad4 = (lane>>4)*4;
  #pragma unroll
  for (int mi=0;mi<4;mi++){
    #pragma unroll
    for (int ni=0;ni<2;ni++){
      int cg = n0 + wn*32 + ni*16 + ln16;
      int which = cg/768; int rem = cg - which*768;
      int h = rem>>6, dd = rem&63;
      #pragma unroll
      for (int r=0;r<4;r++){
        int m = m0 + wm*64 + mi*16 + quad4 + r;
        int bb = m>>10, n = m&1023;
        float val = acc[mi][ni][r];
        if (which==0)      q [((size_t)(bb*NH+h)*SEQ + n)*DH + dd] = f2b(val*(SCALE*LOG2E));
        else if (which==1) k [((size_t)(bb*NH+h)*SEQ + n)*DH + dd] = f2b(val);
        else               vt[((size_t)(bb*NH+h)*DH + dd)*SEQ + n] = f2b(val);
      }
    }
  }
}

// ---------------- pass 1: l += sum exp2(s); stash packed-bf16 exp to global ----------------
__global__ __launch_bounds__(768) void attn_sums(const bf16* __restrict__ q,
                                                 const bf16* __restrict__ k,
                                                 float* __restrict__ l,
                                                 u64* __restrict__ pst){
  int rg = blockIdx.x, ch = blockIdx.y, b = blockIdx.z; int r0 = rg*16;
  int t = threadIdx.x; int h = t>>6; int lane = t&63;
  int ln16 = lane&15, quad = lane>>4; int q8 = quad*8, quad4 = quad*4;
  const bf16* qrow = q + ((size_t)(b*NH+h)*SEQ + r0 + ln16)*DH;
  short8 aq0 = *(const short8*)(qrow + q8);
  short8 aq1 = *(const short8*)(qrow + 32 + q8);
  const bf16* kB = k + ((size_t)(b*NH+h)*SEQ)*DH;
  u64* pb = pst + ((((size_t)(b*NCH+ch)*64 + rg)*NH + h)*16)*64 + lane;
  float ls[4] = {0.f,0.f,0.f,0.f};
  #pragma unroll 4
  for (int i=0;i<16;i++){
    int c0 = ch*256 + i*16;
    const bf16* krow = kB + (size_t)(c0 + ln16)*DH;
    short8 bk0 = *(const short8*)(krow + q8);
    short8 bk1 = *(const short8*)(krow + 32 + q8);
    f32x4 a = {0.f,0.f,0.f,0.f};
    a = __builtin_amdgcn_mfma_f32_16x16x32_bf16(aq0, bk0, a, 0, 0, 0);
    a = __builtin_amdgcn_mfma_f32_16x16x32_bf16(aq1, bk1, a, 0, 0, 0);
    float e0 = exp2f(a[0]), e1 = exp2f(a[1]), e2 = exp2f(a[2]), e3 = exp2f(a[3]);
    ls[0]+=e0; ls[1]+=e1; ls[2]+=e2; ls[3]+=e3;
    unsigned p0 = ((unsigned)(unsigned short)f2bs(e1) << 16) | (unsigned)(unsigned short)f2bs(e0);
    unsigned p1 = ((unsigned)(unsigned short)f2bs(e3) << 16) | (unsigned)(unsigned short)f2bs(e2);
    pb[(size_t)i*64] = ((u64)p1 << 32) | (u64)p0;
  }
  #pragma unroll
  for (int msk=1; msk<16; msk<<=1){
    #pragma unroll
    for (int r=0;r<4;r++) ls[r] += __shfl_xor(ls[r], msk);
  }
  if (ln16 == 0){
    #pragma unroll
    for (int r=0;r<4;r++)
      atomicAdd(&l[((size_t)(b*NH+h))*SEQ + r0 + quad4 + r], ls[r]);
  }
}

// ---------------- pass 2: 1-barrier/iter pipelined {B_i | C_{i-1} | A_{i+1}}  [r12-verified] ----------------
__global__ __launch_bounds__(768, 6) void attn_main(const bf16* __restrict__ vt,
                                                    const bf16* __restrict__ Mb,
                                                    const float* __restrict__ l,
                                                    const u64* __restrict__ pst,
                                                    bf16* __restrict__ opart){
  __shared__ __align__(16) bf16 attJ[2][16*AJ_RS];   // 2 x 20736 B
  __shared__ __align__(16) bf16 combT[2][12*CT_HS];  // 2 x 15552 B  (total 72.5 KB)
  int rg = blockIdx.x, ch = blockIdx.y, b = blockIdx.z; int r0 = rg*16;
  int t = threadIdx.x; int h = t>>6; int lane = t&63;
  int ln16 = lane&15, quad = lane>>4; int q8 = quad*8, quad4 = quad*4;
  const bf16* vB = vt + ((size_t)(b*NH+h)*DH)*SEQ;
  const u64* pb = pst + ((((size_t)(b*NCH+ch)*64 + rg)*NH + h)*16)*64 + lane;

  // one-time: zero both attJ buffers (j 12..15 pad must be exact zero)
  short8 z8 = (short8){0,0,0,0,0,0,0,0};
  bf16* aj = (bf16*)attJ;
  for (int i = t*8; i < 2*16*AJ_RS; i += 768*8) *(short8*)&aj[i] = z8;

  // mix-matrix A-frags, K=16 layout: M[ln16][quad*4+e], hi+lo bf16
  short4v mhi4 = *(const short4v*)&Mb[ln16*16 + quad*4];
  short4v mlo4 = *(const short4v*)&Mb[256 + ln16*16 + quad*4];

  float inv_l[4];
  #pragma unroll
  for (int r=0;r<4;r++) inv_l[r] = 1.0f / l[((size_t)(b*NH+h))*SEQ + r0 + quad4 + r];

  // phase A: unpack stash pair -> attJ[bb] (r,cc,j=h), j-stride 20
  auto A_phase = [&](int bb, u64 c0q, u64 c1q){
    bf16* dst = &attJ[bb][0];
    #pragma unroll
    for (int half=0; half<2; half++){
      int cc = half*16 + ln16;
      u64 cu = half ? c1q : c0q;
      unsigned p0 = (unsigned)cu, p1 = (unsigned)(cu >> 32);
      dst[(quad4+0)*AJ_RS + cc*20 + h] = f2b(s2f((short)(p0 & 0xffff))*inv_l[0]);
      dst[(quad4+1)*AJ_RS + cc*20 + h] = f2b(s2f((short)(p0 >> 16))   *inv_l[1]);
      dst[(quad4+2)*AJ_RS + cc*20 + h] = f2b(s2f((short)(p1 & 0xffff))*inv_l[2]);
      dst[(quad4+3)*AJ_RS + cc*20 + h] = f2b(s2f((short)(p1 >> 16))   *inv_l[3]);
    }
  };
  // phase B tile: C[16h][16pos] = M(hi/lo) x attJ via 2x mfma 16x16x16; +identity, relu
  auto mixTile = [&](const bf16* src, bf16* dstC, int tl){
    int n = tl*16 + ln16;                  // pos = r*32 + cc
    int base = (n>>5)*AJ_RS + (n&31)*20;
    short4v bfrag = *(const short4v*)&src[base + quad*4];   // B[k=j][n=pos]
    f32x4 c = {0.f,0.f,0.f,0.f};
    c = __builtin_amdgcn_mfma_f32_16x16x16bf16_1k(mlo4, bfrag, c, 0, 0, 0);
    c = __builtin_amdgcn_mfma_f32_16x16x16bf16_1k(mhi4, bfrag, c, 0, 0, 0);
    s2v id01 = *(const s2v*)&src[base + quad4];             // identity term
    s2v id23 = *(const s2v*)&src[base + quad4 + 2];
    float idf[4] = { s2f(id01[0]), s2f(id01[1]), s2f(id23[0]), s2f(id23[1]) };
    int cbase = (n>>5)*40 + (n&31);
    if (quad < 3){
      #pragma unroll
      for (int ri=0; ri<4; ri++)
        dstC[(quad4+ri)*CT_HS + cbase] = f2b(idf[ri] + fmaxf(c[ri], 0.f));
    }
  };

  u64 cur0 = pb[0], cur1 = pb[64];
  __syncthreads();                         // attJ zeros visible
  A_phase(0, cur0, cur1);
  u64 nx0 = pb[2*64], nx1 = pb[3*64];

  f32x4 oacc[4] = {};
  short8 vv0, vv1, vv2, vv3;
  for (int it=0; it<8; it++){
    int bb = it&1;
    if (it > 0){                           // V for chunk it-1 (consumed by C after bar)
      const bf16* vp = vB + (size_t)ln16*SEQ + ch*256 + (it-1)*32 + q8;
      vv0 = *(const short8*)(vp);
      vv1 = *(const short8*)(vp + 16*SEQ);
      vv2 = *(const short8*)(vp + 32*SEQ);
      vv3 = *(const short8*)(vp + 48*SEQ);
    }
    __syncthreads();                       // the ONE barrier per iteration
    // B_it: attJ[bb] -> combT[bb]  (2 unrolled tiles + wave-uniform tail)
    mixTile(&attJ[bb][0], &combT[bb][0], h);
    mixTile(&attJ[bb][0], &combT[bb][0], h + 12);
    if (h < 8) mixTile(&attJ[bb][0], &combT[bb][0], h + 24);
    // C_{it-1}: PV MFMA from combT[bb^1]
    if (it > 0){
      short8 afrag = *(const short8*)&combT[bb^1][h*CT_HS + ln16*40 + q8];
      oacc[0] = __builtin_amdgcn_mfma_f32_16x16x32_bf16(afrag, vv0, oacc[0], 0, 0, 0);
      oacc[1] = __builtin_amdgcn_mfma_f32_16x16x32_bf16(afrag, vv1, oacc[1], 0, 0, 0);
      oacc[2] = __builtin_amdgcn_mfma_f32_16x16x32_bf16(afrag, vv2, oacc[2], 0, 0, 0);
      oacc[3] = __builtin_amdgcn_mfma_f32_16x16x32_bf16(afrag, vv3, oacc[3], 0, 0, 0);
    }
    // A_{it+1}: unpack next stash pair -> attJ[bb^1]
    if (it < 7){
      A_phase(bb^1, nx0, nx1);
      if (it < 6){
        nx0 = pb[(size_t)((it+2)*2)*64];
        nx1 = pb[(size_t)((it+2)*2+1)*64];
      }
    }
  }
  // epilogue: C_7
  {
    const bf16* vp = vB + (size_t)ln16*SEQ + ch*256 + 7*32 + q8;
    vv0 = *(const short8*)(vp);
    vv1 = *(const short8*)(vp + 16*SEQ);
    vv2 = *(const short8*)(vp + 32*SEQ);
    vv3 = *(const short8*)(vp + 48*SEQ);
  }
  __syncthreads();
  {
    short8 afrag = *(const short8*)&combT[1][h*CT_HS + ln16*40 + q8];  // 7&1
    oacc[0] = __builtin_amdgcn_mfma_f32_16x16x32_bf16(afrag, vv0, oacc[0], 0, 0, 0);
    oacc[1] = __builtin_amdgcn_mfma_f32_16x16x32_bf16(afrag, vv1, oacc[1], 0, 0, 0);
    oacc[2] = __builtin_amdgcn_mfma_f32_16x16x32_bf16(afrag, vv2, oacc[2], 0, 0, 0);
    oacc[3] = __builtin_amdgcn_mfma_f32_16x16x32_bf16(afrag, vv3, oacc[3], 0, 0, 0);
  }
  // epilogue: bf16 partial O for this chunk
  bf16* dst = opart + ((size_t)ch*NB*SEQ + (size_t)b*SEQ)*DMODEL;
  #pragma unroll
  for (int ni=0; ni<4; ni++)
    #pragma unroll
    for (int r=0; r<4; r++){
      int n = r0 + quad4 + r;
      dst[(size_t)n*DMODEL + h*DH + ni*16 + ln16] = f2b(oacc[ni][r]);
    }
}

// ---------------- reduce partials (bf16): aout = bf16( sum_ch opart )  [r0-verified] ----------------
__global__ __launch_bounds__(256) void reduce_kernel(const bf16* __restrict__ opart,
                                                     bf16* __restrict__ aout){
  const size_t TOT = (size_t)NB*SEQ*DMODEL;      // 1,572,864
  size_t i = ((size_t)blockIdx.x*256 + threadIdx.x)*8;
  float s[8] = {};
  #pragma unroll
  for (int c=0;c<NCH;c++){
    short8 u = *(const short8*)&opart[c*TOT + i];
    #pragma unroll
    for (int e=0;e<8;e++) s[e] += s2f(u[e]);
  }
  short8 o;
  #pragma unroll
  for (int e=0;e<8;e++) o[e] = f2bs(s[e]);
  *(short8*)&aout[i] = o;
}

// ---------------- out proj (MFMA, 64x64 tiles, LDS-dbuf 1-bar/K-step) ----------------
// Same dbuf transform as gemm_qkv — 24 barriers vs 48, staging loads overlap
// the MFMA phase instead of draining naked at each half-step.
__global__ __launch_bounds__(256) void gemm_out(const bf16* __restrict__ A,
                                                const bf16* __restrict__ W,
                                                const float* __restrict__ bias,
                                                float* __restrict__ out){
  __shared__ bf16 As[2][64*32];
  __shared__ bf16 Bs[2][64*32];
  int n0 = blockIdx.x*64, m0 = blockIdx.y*64;
  int t = threadIdx.x, w = t>>6, lane = t&63;
  int ln16 = lane&15, q8 = (lane>>4)*8;
  int wm = w>>1, wn = w&1;
  f32x4 acc[2][2] = {};
  int r = t>>2, ko = (t&3)*8;
  // prologue: stage K-step 0 into buffer 0
  gl_lds16(&A[(size_t)(m0+r)*768 + ko], &As[0][(size_t)(w*64)*8]);
  gl_lds16(&W[(size_t)(n0+r)*768 + ko], &Bs[0][(size_t)(w*64)*8]);
  for (int it=0; it<24; it++){
    int buf = it&1;
    __syncthreads();          // buf ready; buf^1 free
    if (it < 23){
      int k0n = (it+1)*32;
      gl_lds16(&A[(size_t)(m0+r)*768 + k0n+ko], &As[buf^1][(size_t)(w*64)*8]);
      gl_lds16(&W[(size_t)(n0+r)*768 + k0n+ko], &Bs[buf^1][(size_t)(w*64)*8]);
    }
    short8 af[2], bfr[2];
    #pragma unroll
    for (int mi=0;mi<2;mi++) af[mi]  = *(const short8*)&As[buf][(wm*32+mi*16+ln16)*32 + q8];
    #pragma unroll
    for (int ni=0;ni<2;ni++) bfr[ni] = *(const short8*)&Bs[buf][(wn*32+ni*16+ln16)*32 + q8];
    #pragma unroll
    for (int mi=0;mi<2;mi++)
      #pragma unroll
      for (int ni=0;ni<2;ni++)
        acc[mi][ni] = __builtin_amdgcn_mfma_f32_16x16x32_bf16(af[mi], bfr[ni], acc[mi][ni], 0, 0, 0);
  }
  int quad4 = (lane>>4)*4;
  #pragma unroll
  for (int mi=0;mi<2;mi++)
    #pragma unroll
    for (int ni=0;ni<2;ni++){
      int cg = n0 + wn*32 + ni*16 + ln16;
      #pragma unroll
      for (int rr=0;rr<4;rr++){
        int m = m0 + wm*32 + mi*16 + quad4 + rr;
        out[(size_t)m*768 + cg] = acc[mi][ni][rr] + bias[cg];
      }
    }
}

extern "C" void kernel_launch(void* const* d_in, const int* in_sizes, int n_in,
                              void* d_out, int out_size, void* d_ws, size_t ws_size,
                              hipStream_t stream){
  const float* x     = (const float*)d_in[0];
  const float* ln_g  = (const float*)d_in[1];
  const float* ln_b  = (const float*)d_in[2];
  const float* w_qkv = (const float*)d_in[3];
  const float* w_out = (const float*)d_in[4];
  const float* b_out = (const float*)d_in[5];
  const float* theta = (const float*)d_in[6];
  const float* gnn   = (const float*)d_in[7];
  float* out = (float*)d_out;

  char* p = (char*)d_ws;
  bf16* xnb   = (bf16*)p; p += (size_t)2048*768*2;
  bf16* wqkvb = (bf16*)p; p += (size_t)2304*768*2;
  bf16* woutb = (bf16*)p; p += (size_t)768*768*2;   // contiguous after wqkvb
  bf16* qb    = (bf16*)p; p += (size_t)NB*NH*SEQ*DH*2;
  bf16* kb    = (bf16*)p; p += (size_t)NB*NH*SEQ*DH*2;
  bf16* vtb   = (bf16*)p; p += (size_t)NB*NH*SEQ*DH*2;
  bf16* aoutb = (bf16*)p; p += (size_t)2048*768*2;
  bf16* Mbw   = (bf16*)p; p += (size_t)1024*2;      // [2][16][16] hi/lo bf16
  float* lsum = (float*)p; p += (size_t)NB*NH*SEQ*4;
  bf16* opart = (bf16*)p; p += (size_t)NCH*NB*SEQ*DMODEL*2;  // 12.6 MB
  u64*  pstw  = (u64*)p;                            // full P stash: 50.3 MB

  const int N1 = 2304*768, N2 = 768*768;
  prep_all<<<dim3(2048+2304+97), dim3(256), 0, stream>>>(
      x, ln_g, ln_b, w_qkv, N1, w_out, N2, theta, gnn, xnb, wqkvb, Mbw, lsum);
  gemm_qkv<<<dim3(36, 16), dim3(256), 0, stream>>>(xnb, wqkvb, qb, kb, vtb);
  attn_sums<<<dim3(64, NCH, NB), dim3(768), 0, stream>>>(qb, kb, lsum, pstw);
  attn_main<<<dim3(64, NCH, NB), dim3(768), 0, stream>>>(vtb, Mbw, lsum, pstw, opart);
  reduce_kernel<<<dim3(NB*SEQ*DMODEL/(8*256)), dim3(256), 0, stream>>>(opart, aoutb);
  gemm_out<<<dim3(12, 32), dim3(256), 0, stream>>>(aoutb, woutb, b_out, out);
}

// Round 15
// 176.197 us; speedup vs baseline: 1.0230x; 1.0230x over previous
//
#include <hip/hip_runtime.h>
#include <hip/hip_bf16.h>
#include <stdint.h>

#define NB 2
#define SEQ 1024
#define DMODEL 768
#define NH 12
#define DH 64
#define SCALE 0.125f
#define LOG2E 1.44269504088896f
#define NCH 4          // column chunks in fused attention

// attJ (per buffer): [16 rows][32 cols][20 j]  j-stride 20 shorts, row-stride 648
#define AJ_RS 648
// combT (per buffer): [12 heads][16 rows][40 cols-pad], head-stride 648 shorts
#define CT_HS 648

typedef __hip_bfloat16 bf16;
typedef __attribute__((ext_vector_type(8))) short short8;   // 8 x bf16 = 4 VGPRs
typedef __attribute__((ext_vector_type(4))) short short4v;  // 4 x bf16 (8B)
typedef __attribute__((ext_vector_type(2))) short s2v;      // 2 x bf16 (4B aligned)
typedef __attribute__((ext_vector_type(4))) float f32x4;    // MFMA C/D
typedef unsigned long long u64;

__device__ __forceinline__ bf16 f2b(float x){ return __float2bfloat16(x); }
__device__ __forceinline__ short f2bs(float x){
  bf16 h = __float2bfloat16(x); return *reinterpret_cast<short*>(&h);
}
__device__ __forceinline__ float s2f(short u){
  return __uint_as_float(((unsigned)(unsigned short)u) << 16);
}

// async global->LDS 16B: LDS dest wave-uniform base; HW adds lane*16.
__device__ __forceinline__ void gl_lds16(const bf16* g, bf16* l){
  __builtin_amdgcn_global_load_lds(
      (const __attribute__((address_space(1))) void*)g,
      (__attribute__((address_space(3))) void*)l, 16, 0, 0);
}

// ---------------- merged prelude: LN rows (wave-reduce) | weight cvt (float4) | M + lsum zero ----------------
__global__ __launch_bounds__(256) void prep_all(const float* __restrict__ x,
                                                const float* __restrict__ g,
                                                const float* __restrict__ bta,
                                                const float* __restrict__ w1, int n1,
                                                const float* __restrict__ w2, int n2,
                                                const float* __restrict__ theta,
                                                const float* __restrict__ gnn,
                                                bf16* __restrict__ xn,
                                                bf16* __restrict__ wb,
                                                bf16* __restrict__ Mb,
                                                float* __restrict__ l){
  int bx = blockIdx.x, t = threadIdx.x;
  if (bx < 2048){
    const float* xr = x + (size_t)bx*DMODEL;
    float v0[3]; float s = 0.f, s2 = 0.f;
    #pragma unroll
    for (int i=0;i<3;i++){ float val = xr[t+256*i]; v0[i]=val; s+=val; s2+=val*val; }
    // wave-level reduce (6 shfl steps) + 4-partial LDS combine: 1 barrier vs old 8
    #pragma unroll
    for (int m=1;m<64;m<<=1){ s += __shfl_xor(s,m); s2 += __shfl_xor(s2,m); }
    __shared__ float pw[4], pw2[4];
    int wv = t>>6;
    if ((t&63)==0){ pw[wv]=s; pw2[wv]=s2; }
    __syncthreads();
    float fs  = pw[0]+pw[1]+pw[2]+pw[3];
    float fs2 = pw2[0]+pw2[1]+pw2[2]+pw2[3];
    float mean = fs*(1.f/DMODEL);
    float var  = fs2*(1.f/DMODEL) - mean*mean;
    float rstd = rsqrtf(var + 1e-5f);
    #pragma unroll
    for (int i=0;i<3;i++){
      int c = t+256*i;
      xn[(size_t)bx*DMODEL + c] = f2b((v0[i]-mean)*rstd*g[c] + bta[c]);
    }
  } else if (bx < 2048+2304){
    // weight cvt, float4-vectorized: (n1+n2)/4 = 589824 elems4 = 2304 blocks x 256
    int i = ((bx-2048)*256 + t)*4;         // n1 divisible by 4 -> no straddle
    const float* src = (i < n1) ? (w1 + i) : (w2 + (i - n1));
    float4 v = *(const float4*)src;
    short4v o = { f2bs(v.x), f2bs(v.y), f2bs(v.z), f2bs(v.w) };
    *(short4v*)&wb[i] = o;
  } else {
    int sub = bx - (2048+2304);
    if (sub == 0){
      // M = (-0.5*theta) @ gnn_w, zero-padded to [16][16] (K=16 mix), split hi+lo bf16
      if (t < 256){
        int i = t >> 4, j = t & 15;
        float sacc = 0.f;
        if (i < 12 && j < 12)
          for (int jj=0;jj<12;jj++) sacc += (-0.5f)*theta[i*12+jj] * gnn[jj*12+j];
        bf16 hi = f2b(sacc);
        float lo = sacc - __bfloat162float(hi);
        Mb[t]       = hi;
        Mb[256 + t] = f2b(lo);
      }
    } else {
      l[(sub-1)*256 + t] = 0.f;    // 96*256 = 24576 = 2*12*1024
    }
  }
}

// ---------------- QKV GEMM (MFMA, 128x64 tiles): xn[2048,768] @ wqkv^T ----------------
// grid (36,16)=576 blocks = 2.25/CU (r11-verified). Single-buffer staging: r14 proved
// the dbuf 1-bar variant is neutral/negative (TLP from 4+ resident blocks already
// hides staging latency; dbuf only doubled LDS). Q pre-scaled by SCALE*LOG2E -> exp2f.
__global__ __launch_bounds__(256) void gemm_qkv(const bf16* __restrict__ A,
                                                const bf16* __restrict__ W,
                                                bf16* __restrict__ q,
                                                bf16* __restrict__ k,
                                                bf16* __restrict__ vt){
  __shared__ bf16 As[128*32];
  __shared__ bf16 Bs[64*32];
  int n0 = blockIdx.x*64, m0 = blockIdx.y*128;
  int t = threadIdx.x, w = t>>6, lane = t&63;
  int ln16 = lane&15, q8 = (lane>>4)*8;
  int wm = w>>1, wn = w&1;
  f32x4 acc[4][2] = {};
  int rB = t>>2, koB = (t&3)*8;
  for (int k0=0; k0<768; k0+=32){
    __syncthreads();
    #pragma unroll
    for (int i=0;i<2;i++){
      int cc = t + i*256;
      int r = cc>>2, ko = (cc&3)*8;
      gl_lds16(&A[(size_t)(m0+r)*768 + k0+ko], &As[(size_t)(w*64 + i*256)*8]);
    }
    gl_lds16(&W[(size_t)(n0+rB)*768 + k0+koB], &Bs[(size_t)(w*64)*8]);
    __syncthreads();
    short8 af[4], bfr[2];
    #pragma unroll
    for (int mi=0;mi<4;mi++) af[mi]  = *(const short8*)&As[(wm*64+mi*16+ln16)*32 + q8];
    #pragma unroll
    for (int ni=0;ni<2;ni++) bfr[ni] = *(const short8*)&Bs[(wn*32+ni*16+ln16)*32 + q8];
    #pragma unroll
    for (int mi=0;mi<4;mi++)
      #pragma unroll
      for (int ni=0;ni<2;ni++)
        acc[mi][ni] = __builtin_amdgcn_mfma_f32_16x16x32_bf16(af[mi], bfr[ni], acc[mi][ni], 0, 0, 0);
  }
  int quad4 = (lane>>4)*4;
  #pragma unroll
  for (int mi=0;mi<4;mi++){
    #pragma unroll
    for (int ni=0;ni<2;ni++){
      int cg = n0 + wn*32 + ni*16 + ln16;
      int which = cg/768; int rem = cg - which*768;
      int h = rem>>6, dd = rem&63;
      #pragma unroll
      for (int r=0;r<4;r++){
        int m = m0 + wm*64 + mi*16 + quad4 + r;
        int bb = m>>10, n = m&1023;
        float val = acc[mi][ni][r];
        if (which==0)      q [((size_t)(bb*NH+h)*SEQ + n)*DH + dd] = f2b(val*(SCALE*LOG2E));
        else if (which==1) k [((size_t)(bb*NH+h)*SEQ + n)*DH + dd] = f2b(val);
        else               vt[((size_t)(bb*NH+h)*DH + dd)*SEQ + n] = f2b(val);
      }
    }
  }
}

// ---------------- pass 1: l += sum exp2(s); stash packed-bf16 exp to global ----------------
__global__ __launch_bounds__(768) void attn_sums(const bf16* __restrict__ q,
                                                 const bf16* __restrict__ k,
                                                 float* __restrict__ l,
                                                 u64* __restrict__ pst){
  int rg = blockIdx.x, ch = blockIdx.y, b = blockIdx.z; int r0 = rg*16;
  int t = threadIdx.x; int h = t>>6; int lane = t&63;
  int ln16 = lane&15, quad = lane>>4; int q8 = quad*8, quad4 = quad*4;
  const bf16* qrow = q + ((size_t)(b*NH+h)*SEQ + r0 + ln16)*DH;
  short8 aq0 = *(const short8*)(qrow + q8);
  short8 aq1 = *(const short8*)(qrow + 32 + q8);
  const bf16* kB = k + ((size_t)(b*NH+h)*SEQ)*DH;
  u64* pb = pst + ((((size_t)(b*NCH+ch)*64 + rg)*NH + h)*16)*64 + lane;
  float ls[4] = {0.f,0.f,0.f,0.f};
  #pragma unroll 4
  for (int i=0;i<16;i++){
    int c0 = ch*256 + i*16;
    const bf16* krow = kB + (size_t)(c0 + ln16)*DH;
    short8 bk0 = *(const short8*)(krow + q8);
    short8 bk1 = *(const short8*)(krow + 32 + q8);
    f32x4 a = {0.f,0.f,0.f,0.f};
    a = __builtin_amdgcn_mfma_f32_16x16x32_bf16(aq0, bk0, a, 0, 0, 0);
    a = __builtin_amdgcn_mfma_f32_16x16x32_bf16(aq1, bk1, a, 0, 0, 0);
    float e0 = exp2f(a[0]), e1 = exp2f(a[1]), e2 = exp2f(a[2]), e3 = exp2f(a[3]);
    ls[0]+=e0; ls[1]+=e1; ls[2]+=e2; ls[3]+=e3;
    unsigned p0 = ((unsigned)(unsigned short)f2bs(e1) << 16) | (unsigned)(unsigned short)f2bs(e0);
    unsigned p1 = ((unsigned)(unsigned short)f2bs(e3) << 16) | (unsigned)(unsigned short)f2bs(e2);
    pb[(size_t)i*64] = ((u64)p1 << 32) | (u64)p0;
  }
  #pragma unroll
  for (int msk=1; msk<16; msk<<=1){
    #pragma unroll
    for (int r=0;r<4;r++) ls[r] += __shfl_xor(ls[r], msk);
  }
  if (ln16 == 0){
    #pragma unroll
    for (int r=0;r<4;r++)
      atomicAdd(&l[((size_t)(b*NH+h))*SEQ + r0 + quad4 + r], ls[r]);
  }
}

// ---------------- pass 2: 1-barrier/iter pipelined {B_i | C_{i-1} | A_{i+1}}  [r12-verified] ----------------
__global__ __launch_bounds__(768, 6) void attn_main(const bf16* __restrict__ vt,
                                                    const bf16* __restrict__ Mb,
                                                    const float* __restrict__ l,
                                                    const u64* __restrict__ pst,
                                                    bf16* __restrict__ opart){
  __shared__ __align__(16) bf16 attJ[2][16*AJ_RS];   // 2 x 20736 B
  __shared__ __align__(16) bf16 combT[2][12*CT_HS];  // 2 x 15552 B  (total 72.5 KB)
  int rg = blockIdx.x, ch = blockIdx.y, b = blockIdx.z; int r0 = rg*16;
  int t = threadIdx.x; int h = t>>6; int lane = t&63;
  int ln16 = lane&15, quad = lane>>4; int q8 = quad*8, quad4 = quad*4;
  const bf16* vB = vt + ((size_t)(b*NH+h)*DH)*SEQ;
  const u64* pb = pst + ((((size_t)(b*NCH+ch)*64 + rg)*NH + h)*16)*64 + lane;

  // one-time: zero both attJ buffers (j 12..15 pad must be exact zero)
  short8 z8 = (short8){0,0,0,0,0,0,0,0};
  bf16* aj = (bf16*)attJ;
  for (int i = t*8; i < 2*16*AJ_RS; i += 768*8) *(short8*)&aj[i] = z8;

  // mix-matrix A-frags, K=16 layout: M[ln16][quad*4+e], hi+lo bf16
  short4v mhi4 = *(const short4v*)&Mb[ln16*16 + quad*4];
  short4v mlo4 = *(const short4v*)&Mb[256 + ln16*16 + quad*4];

  float inv_l[4];
  #pragma unroll
  for (int r=0;r<4;r++) inv_l[r] = 1.0f / l[((size_t)(b*NH+h))*SEQ + r0 + quad4 + r];

  // phase A: unpack stash pair -> attJ[bb] (r,cc,j=h), j-stride 20
  auto A_phase = [&](int bb, u64 c0q, u64 c1q){
    bf16* dst = &attJ[bb][0];
    #pragma unroll
    for (int half=0; half<2; half++){
      int cc = half*16 + ln16;
      u64 cu = half ? c1q : c0q;
      unsigned p0 = (unsigned)cu, p1 = (unsigned)(cu >> 32);
      dst[(quad4+0)*AJ_RS + cc*20 + h] = f2b(s2f((short)(p0 & 0xffff))*inv_l[0]);
      dst[(quad4+1)*AJ_RS + cc*20 + h] = f2b(s2f((short)(p0 >> 16))   *inv_l[1]);
      dst[(quad4+2)*AJ_RS + cc*20 + h] = f2b(s2f((short)(p1 & 0xffff))*inv_l[2]);
      dst[(quad4+3)*AJ_RS + cc*20 + h] = f2b(s2f((short)(p1 >> 16))   *inv_l[3]);
    }
  };
  // phase B tile: C[16h][16pos] = M(hi/lo) x attJ via 2x mfma 16x16x16; +identity, relu
  auto mixTile = [&](const bf16* src, bf16* dstC, int tl){
    int n = tl*16 + ln16;                  // pos = r*32 + cc
    int base = (n>>5)*AJ_RS + (n&31)*20;
    short4v bfrag = *(const short4v*)&src[base + quad*4];   // B[k=j][n=pos]
    f32x4 c = {0.f,0.f,0.f,0.f};
    c = __builtin_amdgcn_mfma_f32_16x16x16bf16_1k(mlo4, bfrag, c, 0, 0, 0);
    c = __builtin_amdgcn_mfma_f32_16x16x16bf16_1k(mhi4, bfrag, c, 0, 0, 0);
    s2v id01 = *(const s2v*)&src[base + quad4];             // identity term
    s2v id23 = *(const s2v*)&src[base + quad4 + 2];
    float idf[4] = { s2f(id01[0]), s2f(id01[1]), s2f(id23[0]), s2f(id23[1]) };
    int cbase = (n>>5)*40 + (n&31);
    if (quad < 3){
      #pragma unroll
      for (int ri=0; ri<4; ri++)
        dstC[(quad4+ri)*CT_HS + cbase] = f2b(idf[ri] + fmaxf(c[ri], 0.f));
    }
  };

  u64 cur0 = pb[0], cur1 = pb[64];
  __syncthreads();                         // attJ zeros visible
  A_phase(0, cur0, cur1);
  u64 nx0 = pb[2*64], nx1 = pb[3*64];

  f32x4 oacc[4] = {};
  short8 vv0, vv1, vv2, vv3;
  for (int it=0; it<8; it++){
    int bb = it&1;
    if (it > 0){                           // V for chunk it-1 (consumed by C after bar)
      const bf16* vp = vB + (size_t)ln16*SEQ + ch*256 + (it-1)*32 + q8;
      vv0 = *(const short8*)(vp);
      vv1 = *(const short8*)(vp + 16*SEQ);
      vv2 = *(const short8*)(vp + 32*SEQ);
      vv3 = *(const short8*)(vp + 48*SEQ);
    }
    __syncthreads();                       // the ONE barrier per iteration
    // B_it: attJ[bb] -> combT[bb]  (2 unrolled tiles + wave-uniform tail)
    mixTile(&attJ[bb][0], &combT[bb][0], h);
    mixTile(&attJ[bb][0], &combT[bb][0], h + 12);
    if (h < 8) mixTile(&attJ[bb][0], &combT[bb][0], h + 24);
    // C_{it-1}: PV MFMA from combT[bb^1]
    if (it > 0){
      short8 afrag = *(const short8*)&combT[bb^1][h*CT_HS + ln16*40 + q8];
      oacc[0] = __builtin_amdgcn_mfma_f32_16x16x32_bf16(afrag, vv0, oacc[0], 0, 0, 0);
      oacc[1] = __builtin_amdgcn_mfma_f32_16x16x32_bf16(afrag, vv1, oacc[1], 0, 0, 0);
      oacc[2] = __builtin_amdgcn_mfma_f32_16x16x32_bf16(afrag, vv2, oacc[2], 0, 0, 0);
      oacc[3] = __builtin_amdgcn_mfma_f32_16x16x32_bf16(afrag, vv3, oacc[3], 0, 0, 0);
    }
    // A_{it+1}: unpack next stash pair -> attJ[bb^1]
    if (it < 7){
      A_phase(bb^1, nx0, nx1);
      if (it < 6){
        nx0 = pb[(size_t)((it+2)*2)*64];
        nx1 = pb[(size_t)((it+2)*2+1)*64];
      }
    }
  }
  // epilogue: C_7
  {
    const bf16* vp = vB + (size_t)ln16*SEQ + ch*256 + 7*32 + q8;
    vv0 = *(const short8*)(vp);
    vv1 = *(const short8*)(vp + 16*SEQ);
    vv2 = *(const short8*)(vp + 32*SEQ);
    vv3 = *(const short8*)(vp + 48*SEQ);
  }
  __syncthreads();
  {
    short8 afrag = *(const short8*)&combT[1][h*CT_HS + ln16*40 + q8];  // 7&1
    oacc[0] = __builtin_amdgcn_mfma_f32_16x16x32_bf16(afrag, vv0, oacc[0], 0, 0, 0);
    oacc[1] = __builtin_amdgcn_mfma_f32_16x16x32_bf16(afrag, vv1, oacc[1], 0, 0, 0);
    oacc[2] = __builtin_amdgcn_mfma_f32_16x16x32_bf16(afrag, vv2, oacc[2], 0, 0, 0);
    oacc[3] = __builtin_amdgcn_mfma_f32_16x16x32_bf16(afrag, vv3, oacc[3], 0, 0, 0);
  }
  // epilogue: bf16 partial O for this chunk
  bf16* dst = opart + ((size_t)ch*NB*SEQ + (size_t)b*SEQ)*DMODEL;
  #pragma unroll
  for (int ni=0; ni<4; ni++)
    #pragma unroll
    for (int r=0; r<4; r++){
      int n = r0 + quad4 + r;
      dst[(size_t)n*DMODEL + h*DH + ni*16 + ln16] = f2b(oacc[ni][r]);
    }
}

// ---------------- reduce partials (bf16): aout = bf16( sum_ch opart )  [r0-verified] ----------------
__global__ __launch_bounds__(256) void reduce_kernel(const bf16* __restrict__ opart,
                                                     bf16* __restrict__ aout){
  const size_t TOT = (size_t)NB*SEQ*DMODEL;      // 1,572,864
  size_t i = ((size_t)blockIdx.x*256 + threadIdx.x)*8;
  float s[8] = {};
  #pragma unroll
  for (int c=0;c<NCH;c++){
    short8 u = *(const short8*)&opart[c*TOT + i];
    #pragma unroll
    for (int e=0;e<8;e++) s[e] += s2f(u[e]);
  }
  short8 o;
  #pragma unroll
  for (int e=0;e<8;e++) o[e] = f2bs(s[e]);
  *(short8*)&aout[i] = o;
}

// ---------------- out proj (MFMA, 64x64 tiles): aout[2048,768] @ w_out^T + b_out -> f32 ----------------
// r0/r12-verified single-buffer async gl_lds16 staging (dbuf variant regressed, r14).
__global__ __launch_bounds__(256) void gemm_out(const bf16* __restrict__ A,
                                                const bf16* __restrict__ W,
                                                const float* __restrict__ bias,
                                                float* __restrict__ out){
  __shared__ bf16 As[64*32];
  __shared__ bf16 Bs[64*32];
  int n0 = blockIdx.x*64, m0 = blockIdx.y*64;
  int t = threadIdx.x, w = t>>6, lane = t&63;
  int ln16 = lane&15, q8 = (lane>>4)*8;
  int wm = w>>1, wn = w&1;
  f32x4 acc[2][2] = {};
  int r = t>>2, ko = (t&3)*8;
  for (int k0=0; k0<768; k0+=32){
    __syncthreads();
    gl_lds16(&A[(size_t)(m0+r)*768 + k0+ko], &As[(size_t)(w*64)*8]);
    gl_lds16(&W[(size_t)(n0+r)*768 + k0+ko], &Bs[(size_t)(w*64)*8]);
    __syncthreads();
    short8 af[2], bfr[2];
    #pragma unroll
    for (int mi=0;mi<2;mi++) af[mi]  = *(const short8*)&As[(wm*32+mi*16+ln16)*32 + q8];
    #pragma unroll
    for (int ni=0;ni<2;ni++) bfr[ni] = *(const short8*)&Bs[(wn*32+ni*16+ln16)*32 + q8];
    #pragma unroll
    for (int mi=0;mi<2;mi++)
      #pragma unroll
      for (int ni=0;ni<2;ni++)
        acc[mi][ni] = __builtin_amdgcn_mfma_f32_16x16x32_bf16(af[mi], bfr[ni], acc[mi][ni], 0, 0, 0);
  }
  int quad4 = (lane>>4)*4;
  #pragma unroll
  for (int mi=0;mi<2;mi++)
    #pragma unroll
    for (int ni=0;ni<2;ni++){
      int cg = n0 + wn*32 + ni*16 + ln16;
      #pragma unroll
      for (int rr=0;rr<4;rr++){
        int m = m0 + wm*32 + mi*16 + quad4 + rr;
        out[(size_t)m*768 + cg] = acc[mi][ni][rr] + bias[cg];
      }
    }
}

extern "C" void kernel_launch(void* const* d_in, const int* in_sizes, int n_in,
                              void* d_out, int out_size, void* d_ws, size_t ws_size,
                              hipStream_t stream){
  const float* x     = (const float*)d_in[0];
  const float* ln_g  = (const float*)d_in[1];
  const float* ln_b  = (const float*)d_in[2];
  const float* w_qkv = (const float*)d_in[3];
  const float* w_out = (const float*)d_in[4];
  const float* b_out = (const float*)d_in[5];
  const float* theta = (const float*)d_in[6];
  const float* gnn   = (const float*)d_in[7];
  float* out = (float*)d_out;

  char* p = (char*)d_ws;
  bf16* xnb   = (bf16*)p; p += (size_t)2048*768*2;
  bf16* wqkvb = (bf16*)p; p += (size_t)2304*768*2;
  bf16* woutb = (bf16*)p; p += (size_t)768*768*2;   // contiguous after wqkvb
  bf16* qb    = (bf16*)p; p += (size_t)NB*NH*SEQ*DH*2;
  bf16* kb    = (bf16*)p; p += (size_t)NB*NH*SEQ*DH*2;
  bf16* vtb   = (bf16*)p; p += (size_t)NB*NH*SEQ*DH*2;
  bf16* aoutb = (bf16*)p; p += (size_t)2048*768*2;
  bf16* Mbw   = (bf16*)p; p += (size_t)1024*2;      // [2][16][16] hi/lo bf16
  float* lsum = (float*)p; p += (size_t)NB*NH*SEQ*4;
  bf16* opart = (bf16*)p; p += (size_t)NCH*NB*SEQ*DMODEL*2;  // 12.6 MB
  u64*  pstw  = (u64*)p;                            // full P stash: 50.3 MB

  const int N1 = 2304*768, N2 = 768*768;
  prep_all<<<dim3(2048+2304+97), dim3(256), 0, stream>>>(
      x, ln_g, ln_b, w_qkv, N1, w_out, N2, theta, gnn, xnb, wqkvb, Mbw, lsum);
  gemm_qkv<<<dim3(36, 16), dim3(256), 0, stream>>>(xnb, wqkvb, qb, kb, vtb);
  attn_sums<<<dim3(64, NCH, NB), dim3(768), 0, stream>>>(qb, kb, lsum, pstw);
  attn_main<<<dim3(64, NCH, NB), dim3(768), 0, stream>>>(vtb, Mbw, lsum, pstw, opart);
  reduce_kernel<<<dim3(NB*SEQ*DMODEL/(8*256)), dim3(256), 0, stream>>>(opart, aoutb);
  gemm_out<<<dim3(12, 32), dim3(256), 0, stream>>>(aoutb, woutb, b_out, out);
}